// Round 1
// baseline (111.842 us; speedup 1.0000x reference)
//
#include <hip/hip_runtime.h>
#include <hip/hip_bf16.h>

typedef __attribute__((ext_vector_type(8))) short bf16x8;
typedef __attribute__((ext_vector_type(4))) float f32x4;
typedef __attribute__((ext_vector_type(4))) unsigned short u16x4;

#define B_DIM 8
#define L_DIM 2048
#define D_DIM 128
#define QBLK 64
#define KVBLK 64
#define RM_ST 136   // 128 + 8 pad (272B rows, 16B-aligned, conflict-free-ish)
#define VT_ST 72    // 64 + 8 pad (144B rows)
#define W_ST 72

__device__ __forceinline__ void split_f32(float f, unsigned short& hi, unsigned short& lo) {
    unsigned u = __float_as_uint(f);
    hi = (unsigned short)(u >> 16);
    float fh = __uint_as_float(u & 0xffff0000u);
    float fl = f - fh;                 // exact residual
    lo = (unsigned short)(__float_as_uint(fl) >> 16);
}

__device__ __forceinline__ unsigned short f2bf(float f) {
    unsigned u = __float_as_uint(f);
    u += 0x7fffu + ((u >> 16) & 1u);   // RNE, inputs never NaN
    return (unsigned short)(u >> 16);
}

__global__ __launch_bounds__(256) void attn_fwd(
    const float* __restrict__ Q, const float* __restrict__ V, float* __restrict__ Out)
{
    __shared__ unsigned short vrm_hi[KVBLK * RM_ST];
    __shared__ unsigned short vrm_lo[KVBLK * RM_ST];
    __shared__ unsigned short vt_hi [D_DIM * VT_ST];
    __shared__ unsigned short w_lds [4 * 16 * W_ST];

    const int tid  = threadIdx.x;
    const int wave = tid >> 6;
    const int lane = tid & 63;
    const int lrow = lane & 15;
    const int lgrp = lane >> 4;

    const int b  = blockIdx.y;
    const int q0 = blockIdx.x * QBLK;
    const int qw = q0 + wave * 16;

    // ---- Q fragments (hi/lo split), held in registers for the whole kernel ----
    bf16x8 qhi[4], qlo[4];
    {
        const float* qp = Q + ((size_t)b * L_DIM + qw + lrow) * D_DIM;
        #pragma unroll
        for (int dt = 0; dt < 4; ++dt) {
            int off = dt * 32 + lgrp * 8;
            f32x4 f0 = *(const f32x4*)(qp + off);
            f32x4 f1 = *(const f32x4*)(qp + off + 4);
            #pragma unroll
            for (int i = 0; i < 4; ++i) {
                unsigned short h, l2;
                split_f32(f0[i], h, l2);
                qhi[dt][i] = (short)h; qlo[dt][i] = (short)l2;
                split_f32(f1[i], h, l2);
                qhi[dt][i + 4] = (short)h; qlo[dt][i + 4] = (short)l2;
            }
        }
    }

    f32x4 acc[8];
    #pragma unroll
    for (int i = 0; i < 8; ++i) acc[i] = (f32x4)0.0f;
    float m_run[4], l_run[4];
    #pragma unroll
    for (int r = 0; r < 4; ++r) { m_run[r] = -1e30f; l_run[r] = 0.0f; }

    unsigned short* wrow = w_lds + wave * (16 * W_ST);

    for (int kt = 0; kt < L_DIM / KVBLK; ++kt) {
        __syncthreads();   // previous tile's LDS reads done before overwrite
        // ---- stage V tile: fp32 -> (hi,lo) bf16; row-major hi/lo + transposed hi ----
        {
            const float* vp = V + ((size_t)b * L_DIM + (size_t)kt * KVBLK) * D_DIM;
            const int dcol = (tid & 31) << 2;   // 0..124
            const int kb0  = (tid >> 5) << 2;   // 0..28
            #pragma unroll
            for (int kh = 0; kh < 2; ++kh) {
                int kb = kb0 + kh * 32;
                f32x4 f[4];
                #pragma unroll
                for (int r = 0; r < 4; ++r)
                    f[r] = *(const f32x4*)(vp + (kb + r) * D_DIM + dcol);
                unsigned short hi[4][4], lo[4][4];
                #pragma unroll
                for (int r = 0; r < 4; ++r) {
                    #pragma unroll
                    for (int i = 0; i < 4; ++i)
                        split_f32(f[r][i], hi[r][i], lo[r][i]);
                }
                #pragma unroll
                for (int r = 0; r < 4; ++r) {
                    u16x4 vh = { hi[r][0], hi[r][1], hi[r][2], hi[r][3] };
                    u16x4 vl = { lo[r][0], lo[r][1], lo[r][2], lo[r][3] };
                    *(u16x4*)&vrm_hi[(kb + r) * RM_ST + dcol] = vh;
                    *(u16x4*)&vrm_lo[(kb + r) * RM_ST + dcol] = vl;
                }
                #pragma unroll
                for (int i = 0; i < 4; ++i) {
                    int d   = dcol + i;
                    int col = kb ^ (((d >> 3) & 7) << 3);   // XOR swizzle on k bits 3-5
                    u16x4 vt = { hi[0][i], hi[1][i], hi[2][i], hi[3][i] };
                    *(u16x4*)&vt_hi[d * VT_ST + col] = vt;
                }
            }
        }
        __syncthreads();

        // ---- QK^T: S[16 q][64 k], 3-pass split precision ----
        f32x4 s[4];
        #pragma unroll
        for (int nt = 0; nt < 4; ++nt) s[nt] = (f32x4)0.0f;
        #pragma unroll
        for (int nt = 0; nt < 4; ++nt) {
            const unsigned short* vr_h = vrm_hi + (nt * 16 + lrow) * RM_ST;
            const unsigned short* vr_l = vrm_lo + (nt * 16 + lrow) * RM_ST;
            #pragma unroll
            for (int dt = 0; dt < 4; ++dt) {
                int off = dt * 32 + lgrp * 8;
                bf16x8 bh = *(const bf16x8*)(vr_h + off);
                bf16x8 bl = *(const bf16x8*)(vr_l + off);
                s[nt] = __builtin_amdgcn_mfma_f32_16x16x32_bf16(qhi[dt], bh, s[nt], 0, 0, 0);
                s[nt] = __builtin_amdgcn_mfma_f32_16x16x32_bf16(qlo[dt], bh, s[nt], 0, 0, 0);
                s[nt] = __builtin_amdgcn_mfma_f32_16x16x32_bf16(qhi[dt], bl, s[nt], 0, 0, 0);
            }
        }

        // ---- online softmax (rows = lgrp*4+r, cols across the 16-lane group) ----
        #pragma unroll
        for (int r = 0; r < 4; ++r) {
            float tmax = fmaxf(fmaxf(s[0][r], s[1][r]), fmaxf(s[2][r], s[3][r]));
            #pragma unroll
            for (int off = 1; off < 16; off <<= 1)
                tmax = fmaxf(tmax, __shfl_xor(tmax, off));
            float mnew  = fmaxf(m_run[r], tmax);
            float scale = __expf(m_run[r] - mnew);
            float psum  = 0.0f;
            #pragma unroll
            for (int nt = 0; nt < 4; ++nt) {
                float p = __expf(s[nt][r] - mnew);
                s[nt][r] = p;
                psum += p;
            }
            #pragma unroll
            for (int off = 1; off < 16; off <<= 1)
                psum += __shfl_xor(psum, off);
            m_run[r] = mnew;
            l_run[r] = l_run[r] * scale + psum;
            #pragma unroll
            for (int nd = 0; nd < 8; ++nd) acc[nd][r] *= scale;
        }

        // ---- P -> bf16 via LDS round-trip into A-fragment layout (wave-local) ----
        #pragma unroll
        for (int r = 0; r < 4; ++r) {
            #pragma unroll
            for (int nt = 0; nt < 4; ++nt)
                wrow[(lgrp * 4 + r) * W_ST + nt * 16 + lrow] = f2bf(s[nt][r]);
        }

        // ---- PV: acc[16 q][128 d] += P * Vhi ----
        #pragma unroll
        for (int kk = 0; kk < 2; ++kk) {
            bf16x8 a = *(const bf16x8*)(wrow + lrow * W_ST + kk * 32 + lgrp * 8);
            #pragma unroll
            for (int nd = 0; nd < 8; ++nd) {
                int d   = nd * 16 + lrow;
                int col = (kk * 32 + lgrp * 8) ^ (((d >> 3) & 7) << 3);
                bf16x8 bv = *(const bf16x8*)(vt_hi + d * VT_ST + col);
                acc[nd] = __builtin_amdgcn_mfma_f32_16x16x32_bf16(a, bv, acc[nd], 0, 0, 0);
            }
        }
    }

    // ---- epilogue: normalize and store fp32 ----
    float* op = Out + ((size_t)b * L_DIM + qw) * D_DIM;
    #pragma unroll
    for (int r = 0; r < 4; ++r) {
        float inv = 1.0f / l_run[r];
        int row = lgrp * 4 + r;
        #pragma unroll
        for (int nd = 0; nd < 8; ++nd)
            op[row * D_DIM + nd * 16 + lrow] = acc[nd][r] * inv;
    }
}

extern "C" void kernel_launch(void* const* d_in, const int* in_sizes, int n_in,
                              void* d_out, int out_size, void* d_ws, size_t ws_size,
                              hipStream_t stream) {
    const float* Q  = (const float*)d_in[0];
    const float* V  = (const float*)d_in[1];
    float* Out      = (float*)d_out;
    dim3 grid(L_DIM / QBLK, B_DIM);
    attn_fwd<<<grid, dim3(256), 0, stream>>>(Q, V, Out);
}

// Round 2
// 63.876 us; speedup vs baseline: 1.7509x; 1.7509x over previous
//
#include <hip/hip_runtime.h>
#include <hip/hip_fp16.h>

typedef _Float16 f16;
typedef __attribute__((ext_vector_type(8))) _Float16 f16x8;
typedef __attribute__((ext_vector_type(4))) _Float16 f16x4;
typedef __attribute__((ext_vector_type(4))) float f32x4;

#define B_DIM 8
#define L_DIM 2048
#define D_DIM 128
#define NGRP 4
#define KVB 64
#define TILES_PER_GRP (L_DIM / KVB / NGRP)   // 8
#define RM_ST 136                            // 272B rows = 17 granules (odd) -> max bank spread
#define VT_ST 72                             // 144B rows = 9 granules (odd)
#define SLAB_ST 129
#define STAGE_BYTES (KVB * RM_ST * 2 + D_DIM * VT_ST * 2)  // 17408 + 18432 = 35840
#define ML_OFF (NGRP * STAGE_BYTES)                        // 143360
#define SMEM_BYTES (ML_OFF + 4 * 4 * 2 * 16 * 4)           // 145408 < 160 KiB

#define MFMA16(a, b, c) __builtin_amdgcn_mfma_f32_16x16x32_f16(a, b, c, 0, 0, 0)

__device__ __forceinline__ unsigned h_bits(f16 h) {
    union { f16 h; unsigned short u; } cv; cv.h = h; return (unsigned)cv.u;
}

__global__ __launch_bounds__(1024, 4) void attn_fwd(
    const float* __restrict__ Q, const float* __restrict__ V, float* __restrict__ Out)
{
    __shared__ __align__(16) char smem[SMEM_BYTES];

    const int tid  = threadIdx.x;
    const int wv   = tid >> 6;
    const int grp  = wv >> 2;    // kv group 0..3
    const int qs   = wv & 3;     // q subtile 0..3
    const int lane = tid & 63;
    const int lrow = lane & 15;
    const int g    = lane >> 4;

    const int blk = blockIdx.x;
    const int b   = blk & 7;             // same batch -> same XCD (round-robin dispatch)
    const int q0  = (blk >> 3) << 6;

    f16*   vhi = (f16*)(smem + grp * STAGE_BYTES);
    f16*   vt  = (f16*)(smem + grp * STAGE_BYTES + KVB * RM_ST * 2);
    float* ml  = (float*)(smem + ML_OFF);

    // ---- Q fragments: fp16 hi/lo split, registers for whole kernel ----
    f16x8 qhi[4], qlo[4];
    {
        const float* qp = Q + ((size_t)b * L_DIM + q0 + qs * 16 + lrow) * D_DIM + g * 8;
        #pragma unroll
        for (int dt = 0; dt < 4; ++dt) {
            f32x4 f0 = *(const f32x4*)(qp + dt * 32);
            f32x4 f1 = *(const f32x4*)(qp + dt * 32 + 4);
            #pragma unroll
            for (int i = 0; i < 4; ++i) {
                f16 h0 = (f16)f0[i];
                qhi[dt][i] = h0;
                qlo[dt][i] = (f16)(f0[i] - (float)h0);
                f16 h1 = (f16)f1[i];
                qhi[dt][i + 4] = h1;
                qlo[dt][i + 4] = (f16)(f1[i] - (float)h1);
            }
        }
    }

    f32x4 acc[8];
    #pragma unroll
    for (int i = 0; i < 8; ++i) acc[i] = (f32x4)0.0f;
    float m_run = -3.0e38f, l_run = 0.0f;

    const int gt = tid & 255;
    const float* vb = V + (size_t)b * L_DIM * D_DIM;

    for (int t = 0; t < TILES_PER_GRP; ++t) {
        const float* vp = vb + (size_t)(grp * TILES_PER_GRP + t) * KVB * D_DIM;
        __syncthreads();   // prior tile's LDS reads done
        // ---- stage V tile: fp32 -> f16, row-major + swizzled transpose ----
        #pragma unroll
        for (int i = 0; i < 8; ++i) {
            int idx = i * 256 + gt;          // coalesced: lane-consecutive 16B
            int kv  = idx >> 5;
            int c   = idx & 31;
            f32x4 f = *(const f32x4*)(vp + kv * D_DIM + c * 4);
            f16 h0 = (f16)f[0], h1 = (f16)f[1], h2 = (f16)f[2], h3 = (f16)f[3];
            f16x4 hv = {h0, h1, h2, h3};
            *(f16x4*)(vhi + kv * RM_ST + c * 4) = hv;
            int d0 = c * 4;
            int kx = kv ^ (((c >> 1) & 7) << 3);   // XOR swizzle on kv bits 3-5 by d>>3
            vt[(d0 + 0) * VT_ST + kx] = h0;
            vt[(d0 + 1) * VT_ST + kx] = h1;
            vt[(d0 + 2) * VT_ST + kx] = h2;
            vt[(d0 + 3) * VT_ST + kx] = h3;
        }
        __syncthreads();

        // ---- QK^T swapped: S^T[kv][q] = mfma(A=V, B=Q), 2-pass fp16 split ----
        f32x4 s[4];
        #pragma unroll
        for (int nt = 0; nt < 4; ++nt) {
            s[nt] = (f32x4)0.0f;
            const f16* vr = vhi + (nt * 16 + lrow) * RM_ST + g * 8;
            #pragma unroll
            for (int dt = 0; dt < 4; ++dt) {
                f16x8 a = *(const f16x8*)(vr + dt * 32);
                s[nt] = MFMA16(a, qhi[dt], s[nt]);
                s[nt] = MFMA16(a, qlo[dt], s[nt]);
            }
        }

        // ---- online softmax: 16 lane-local values per q-col, 2-step shfl ----
        float tmax = fmaxf(fmaxf(s[0][0], s[0][1]), fmaxf(s[0][2], s[0][3]));
        #pragma unroll
        for (int nt = 1; nt < 4; ++nt)
            tmax = fmaxf(tmax, fmaxf(fmaxf(s[nt][0], s[nt][1]), fmaxf(s[nt][2], s[nt][3])));
        tmax = fmaxf(tmax, __shfl_xor(tmax, 16));
        tmax = fmaxf(tmax, __shfl_xor(tmax, 32));
        float mnew = fmaxf(m_run, tmax);
        float scl  = __expf(m_run - mnew);
        float p[4][4];
        float psum = 0.0f;
        #pragma unroll
        for (int nt = 0; nt < 4; ++nt) {
            #pragma unroll
            for (int r = 0; r < 4; ++r) {
                p[nt][r] = __expf(s[nt][r] - mnew);
                psum += p[nt][r];
            }
        }
        psum += __shfl_xor(psum, 16);
        psum += __shfl_xor(psum, 32);
        l_run = l_run * scl + psum;
        m_run = mnew;

        // rescale acc (rows q = g*4+r; scale lives at lane q)
        float sr[4];
        #pragma unroll
        for (int r = 0; r < 4; ++r) sr[r] = __shfl(scl, g * 4 + r);
        #pragma unroll
        for (int nd = 0; nd < 8; ++nd) {
            #pragma unroll
            for (int r = 0; r < 4; ++r) acc[nd][r] *= sr[r];
        }

        // ---- P^T -> P A-fragment via in-register bpermute exchange ----
        unsigned wq[4][2];
        #pragma unroll
        for (int nt = 0; nt < 4; ++nt) {
            wq[nt][0] = h_bits((f16)p[nt][0]) | (h_bits((f16)p[nt][1]) << 16);
            wq[nt][1] = h_bits((f16)p[nt][2]) | (h_bits((f16)p[nt][3]) << 16);
        }
        const int la = lrow + ((g & 1) << 5);
        const int lb = la + 16;
        const bool hi2 = (g & 2);
        f16x8 pa[2];
        #pragma unroll
        for (int kk = 0; kk < 2; ++kk) {
            unsigned a0 = (unsigned)__shfl((int)wq[2 * kk][0], la);
            unsigned a1 = (unsigned)__shfl((int)wq[2 * kk][1], la);
            unsigned a2 = (unsigned)__shfl((int)wq[2 * kk][0], lb);
            unsigned a3 = (unsigned)__shfl((int)wq[2 * kk][1], lb);
            unsigned b0 = (unsigned)__shfl((int)wq[2 * kk + 1][0], la);
            unsigned b1 = (unsigned)__shfl((int)wq[2 * kk + 1][1], la);
            unsigned b2 = (unsigned)__shfl((int)wq[2 * kk + 1][0], lb);
            unsigned b3 = (unsigned)__shfl((int)wq[2 * kk + 1][1], lb);
            union { f16x8 v; unsigned u[4]; } cv;
            cv.u[0] = hi2 ? b0 : a0;
            cv.u[1] = hi2 ? b1 : a1;
            cv.u[2] = hi2 ? b2 : a2;
            cv.u[3] = hi2 ? b3 : a3;
            pa[kk] = cv.v;
        }

        // ---- PV: acc[q][d] += P * Vhi ----
        #pragma unroll
        for (int kk = 0; kk < 2; ++kk) {
            #pragma unroll
            for (int nd = 0; nd < 8; ++nd) {
                int d = nd * 16 + lrow;
                const f16* vr2 = vt + d * VT_ST + ((kk * 32 + g * 8) ^ (((d >> 3) & 7) << 3));
                f16x8 bf = *(const f16x8*)vr2;
                acc[nd] = MFMA16(pa[kk], bf, acc[nd]);
            }
        }
    }

    // ---- cross-group merge ----
    if (g == 0) {
        ml[((qs * 4 + grp) * 2 + 0) * 16 + lrow] = m_run;
        ml[((qs * 4 + grp) * 2 + 1) * 16 + lrow] = l_run;
    }
    __syncthreads();   // also: all PV reads of staging LDS are done -> slabs may overwrite

    float M = -3.0e38f;
    float mg[4], lg[4];
    #pragma unroll
    for (int gg = 0; gg < 4; ++gg) {
        mg[gg] = ml[((qs * 4 + gg) * 2 + 0) * 16 + lrow];
        lg[gg] = ml[((qs * 4 + gg) * 2 + 1) * 16 + lrow];
        M = fmaxf(M, mg[gg]);
    }
    float Lsum = 0.0f;
    #pragma unroll
    for (int gg = 0; gg < 4; ++gg) Lsum += lg[gg] * __expf(mg[gg] - M);
    float myf = __expf(m_run - M);
    float fr[4];
    #pragma unroll
    for (int r = 0; r < 4; ++r) fr[r] = __shfl(myf, g * 4 + r);

    float* slab = (float*)smem + (size_t)(qs * 4 + grp) * (16 * SLAB_ST);
    #pragma unroll
    for (int nd = 0; nd < 8; ++nd) {
        #pragma unroll
        for (int r = 0; r < 4; ++r)
            slab[(g * 4 + r) * SLAB_ST + nd * 16 + lrow] = acc[nd][r] * fr[r];
    }
    __syncthreads();

    float li = 1.0f / Lsum;
    float Linv[4];
    #pragma unroll
    for (int r = 0; r < 4; ++r) Linv[r] = __shfl(li, g * 4 + r);

    float* outp = Out + ((size_t)b * L_DIM + q0 + qs * 16) * D_DIM;
    #pragma unroll
    for (int h = 0; h < 2; ++h) {
        int nd = grp * 2 + h;
        #pragma unroll
        for (int r = 0; r < 4; ++r) {
            float v = 0.0f;
            #pragma unroll
            for (int gg = 0; gg < 4; ++gg)
                v += ((float*)smem)[(size_t)(qs * 4 + gg) * (16 * SLAB_ST) + (g * 4 + r) * SLAB_ST + nd * 16 + lrow];
            outp[(size_t)(g * 4 + r) * D_DIM + nd * 16 + lrow] = v * Linv[r];
        }
    }
}

extern "C" void kernel_launch(void* const* d_in, const int* in_sizes, int n_in,
                              void* d_out, int out_size, void* d_ws, size_t ws_size,
                              hipStream_t stream) {
    const float* Q = (const float*)d_in[0];
    const float* V = (const float*)d_in[1];
    float* Out     = (float*)d_out;
    attn_fwd<<<dim3(B_DIM * (L_DIM / 64)), dim3(1024), 0, stream>>>(Q, V, Out);
}

// Round 3
// 59.023 us; speedup vs baseline: 1.8949x; 1.0822x over previous
//
#include <hip/hip_runtime.h>
#include <hip/hip_fp16.h>

typedef _Float16 f16;
typedef __attribute__((ext_vector_type(8))) _Float16 f16x8;
typedef __attribute__((ext_vector_type(4))) _Float16 f16x4;
typedef __attribute__((ext_vector_type(4))) float f32x4;
typedef __attribute__((ext_vector_type(2))) float f32x2;
typedef __attribute__((ext_vector_type(2))) unsigned u32x2;

#define MFMA16(a,b,c) __builtin_amdgcn_mfma_f32_16x16x32_f16(a,b,c,0,0,0)

#define B_DIM 8
#define L_DIM 2048
#define D_DIM 128
#define NGRP 4
#define KVB 32
#define NTILES 16            // kv tiles per group (512/32)
#define RM_ST 136            // vhi row stride in f16 (272B: bank-optimal for b128 row reads)
#define VT_ST 40             // vt row stride in f16 (80B = 20 granules: bank-optimal)
#define VH_BYTES (KVB * RM_ST * 2)                    // 8704
#define STAGE_B (VH_BYTES + D_DIM * VT_ST * 2)        // 8704 + 10240 = 18944
#define SMEM_B (NGRP * 2 * STAGE_B)                   // 151552
#define SLAB_ST 132
#define P_ST 68              // P row stride in f16 (136B); 32 rows fit exactly in 16*RM_ST slice

__device__ __forceinline__ unsigned pk(f16 lo, f16 hi) {
    union { f16 h[2]; unsigned u; } c; c.h[0] = lo; c.h[1] = hi; return c.u;
}

__device__ __forceinline__ void stage_load(const float* __restrict__ vp, int qw, int lane, f32x4 ld[8]) {
    const int sb = lane & 7, kvq = lane >> 3;
    #pragma unroll
    for (int it = 0; it < 8; ++it) {
        int c8 = qw * 8 + it, oct = c8 >> 2, ds = c8 & 3;
        ld[it] = *(const f32x4*)(vp + (size_t)(oct * 8 + kvq) * D_DIM + ds * 32 + sb * 4);
    }
}

__device__ __forceinline__ void stage_write(f16* vh, f16* vtr, int qw, int lane, const f32x4 ld[8]) {
    const int sb = lane & 7, kvq = lane >> 3;
    #pragma unroll
    for (int it = 0; it < 8; ++it) {
        int c8 = qw * 8 + it, oct = c8 >> 2, ds = c8 & 3;
        int kv = oct * 8 + kvq;
        f16 h0 = (f16)ld[it][0], h1 = (f16)ld[it][1], h2 = (f16)ld[it][2], h3 = (f16)ld[it][3];
        f16x4 hv = { h0, h1, h2, h3 };
        *(f16x4*)(vh + (size_t)kv * RM_ST + ds * 32 + sb * 4) = hv;
        // in-register 4x4 f16 transpose across lanes {l, l^8, l^16, l^24}
        unsigned a = pk(h0, h1), bb = pk(h2, h3);
        unsigned x = (unsigned)__shfl_xor((int)((lane & 16) ? a : bb), 16);
        if (lane & 16) a = x; else bb = x;
        unsigned tp = (lane & 8) ? ((a & 0xffffu) | (bb << 16)) : ((a >> 16) | (bb & 0xffff0000u));
        unsigned r = (unsigned)__shfl_xor((int)tp, 8);
        unsigned o0, o1;
        if (!(lane & 8)) { o0 = (a & 0xffffu) | ((r & 0xffffu) << 16); o1 = (bb & 0xffffu) | (r & 0xffff0000u); }
        else             { o0 = (r & 0xffffu) | (a & 0xffff0000u);     o1 = (r >> 16) | (bb & 0xffff0000u); }
        int d   = ds * 32 + sb * 4 + (kvq & 3);
        int kvc = oct * 8 + (kvq >> 2) * 4;
        u32x2 ov = { o0, o1 };
        *(u32x2*)(vtr + (size_t)d * VT_ST + kvc) = ov;
    }
}

__global__ __launch_bounds__(512, 2) void attn_fwd(
    const float* __restrict__ Q, const float* __restrict__ V, float* __restrict__ Out)
{
    __shared__ __align__(16) char smem[SMEM_B];

    const int tid  = threadIdx.x;
    const int wv   = tid >> 6;
    const int grp  = wv >> 1;     // kv group 0..3 (512 kv each)
    const int qw   = wv & 1;      // q half (32 rows each)
    const int lane = tid & 63;
    const int lrow = lane & 15;
    const int g    = lane >> 4;

    const int blk = blockIdx.x;
    const int b   = blk & 7;
    const int q0  = (blk >> 3) * 64;

    // ---- Q fragments: fp16 hi/lo split, 32 q rows (2 subtiles) ----
    f16x8 qhi[2][4], qlo[2][4];
    {
        const float* qb = Q + ((size_t)b * L_DIM + q0 + qw * 32) * D_DIM;
        #pragma unroll
        for (int qs2 = 0; qs2 < 2; ++qs2) {
            const float* qp = qb + (size_t)(qs2 * 16 + lrow) * D_DIM + g * 8;
            #pragma unroll
            for (int dt = 0; dt < 4; ++dt) {
                f32x4 f0 = *(const f32x4*)(qp + dt * 32);
                f32x4 f1 = *(const f32x4*)(qp + dt * 32 + 4);
                #pragma unroll
                for (int i = 0; i < 4; ++i) {
                    f16 h0 = (f16)f0[i];
                    qhi[qs2][dt][i] = h0;
                    qlo[qs2][dt][i] = (f16)(f0[i] - (float)h0);
                    f16 h1 = (f16)f1[i];
                    qhi[qs2][dt][i + 4] = h1;
                    qlo[qs2][dt][i + 4] = (f16)(f1[i] - (float)h1);
                }
            }
        }
    }

    f32x4 acc[2][8];
    #pragma unroll
    for (int q2 = 0; q2 < 2; ++q2)
        #pragma unroll
        for (int i = 0; i < 8; ++i) acc[q2][i] = (f32x4)0.0f;
    float m_run[2] = { -3.0e38f, -3.0e38f }, l_run[2] = { 0.0f, 0.0f };

    const float* vb = V + ((size_t)b * L_DIM + grp * (L_DIM / NGRP)) * D_DIM;
    f32x4 ld[8];

    // prologue: stage tile 0 into buf 0
    stage_load(vb, qw, lane, ld);
    {
        char* sb0 = smem + (grp * 2 + 0) * STAGE_B;
        stage_write((f16*)sb0, (f16*)(sb0 + VH_BYTES), qw, lane, ld);
    }
    __syncthreads();

    for (int t = 0; t < NTILES; ++t) {
        const int c = t & 1;
        char* sbc = smem + (grp * 2 + c) * STAGE_B;
        char* sba = smem + (grp * 2 + (c ^ 1)) * STAGE_B;
        f16* vh  = (f16*)sbc;
        f16* vtr = (f16*)(sbc + VH_BYTES);

        if (t + 1 < NTILES) stage_load(vb + (size_t)(t + 1) * KVB * D_DIM, qw, lane, ld);

        // ---- QK^T swapped: S^T[kv 32][q 32], fp16 2-pass ----
        f32x4 s[2][2];
        #pragma unroll
        for (int q2 = 0; q2 < 2; ++q2)
            #pragma unroll
            for (int nt = 0; nt < 2; ++nt) s[q2][nt] = (f32x4)0.0f;
        #pragma unroll
        for (int nt = 0; nt < 2; ++nt) {
            const f16* vr = vh + (size_t)(nt * 16 + lrow) * RM_ST + g * 8;
            #pragma unroll
            for (int dt = 0; dt < 4; ++dt) {
                f16x8 a = *(const f16x8*)(vr + dt * 32);
                #pragma unroll
                for (int q2 = 0; q2 < 2; ++q2) {
                    s[q2][nt] = MFMA16(a, qhi[q2][dt], s[q2][nt]);
                    s[q2][nt] = MFMA16(a, qlo[q2][dt], s[q2][nt]);
                }
            }
        }

        // ---- online softmax (per lane: q = lrow [+16*q2], kv = nt*16 + g*4 + r) ----
        float mnew[2], scl[2], psum[2];
        bool grew = false;
        #pragma unroll
        for (int q2 = 0; q2 < 2; ++q2) {
            float t0 = fmaxf(fmaxf(s[q2][0][0], s[q2][0][1]), fmaxf(s[q2][0][2], s[q2][0][3]));
            float t1 = fmaxf(fmaxf(s[q2][1][0], s[q2][1][1]), fmaxf(s[q2][1][2], s[q2][1][3]));
            float tm = fmaxf(t0, t1);
            tm = fmaxf(tm, __shfl_xor(tm, 16));
            tm = fmaxf(tm, __shfl_xor(tm, 32));
            mnew[q2] = fmaxf(m_run[q2], tm);
            grew = grew || (mnew[q2] > m_run[q2]);
            float ps = 0.0f;
            #pragma unroll
            for (int nt = 0; nt < 2; ++nt)
                #pragma unroll
                for (int r = 0; r < 4; ++r) {
                    float p = __expf(s[q2][nt][r] - mnew[q2]);
                    s[q2][nt][r] = p;
                    ps += p;
                }
            ps += __shfl_xor(ps, 16);
            ps += __shfl_xor(ps, 32);
            psum[q2] = ps;
            scl[q2] = __expf(m_run[q2] - mnew[q2]);
            l_run[q2] = l_run[q2] * scl[q2] + ps;
            m_run[q2] = mnew[q2];
        }
        if (__any(grew)) {   // defer-rescale: skip when max unchanged (scl==1 exactly)
            float sr[2][4];
            #pragma unroll
            for (int r = 0; r < 4; ++r) {
                sr[0][r] = __shfl(scl[0], g * 4 + r);
                sr[1][r] = __shfl(scl[1], g * 4 + r);
            }
            #pragma unroll
            for (int q2 = 0; q2 < 2; ++q2)
                #pragma unroll
                for (int nd = 0; nd < 8; ++nd)
                    #pragma unroll
                    for (int r = 0; r < 4; ++r) acc[q2][nd][r] *= sr[q2][r];
        }

        // ---- P -> wave-private LDS slice (dead region of alternate vhi buffer) ----
        f16* pls = (f16*)sba + qw * 16 * RM_ST;   // 32 rows x P_ST f16 == 16*RM_ST exactly
        #pragma unroll
        for (int q2 = 0; q2 < 2; ++q2) {
            #pragma unroll
            for (int nt = 0; nt < 2; ++nt) {
                u32x2 w = { pk((f16)s[q2][nt][0], (f16)s[q2][nt][1]),
                            pk((f16)s[q2][nt][2], (f16)s[q2][nt][3]) };
                *(u32x2*)(pls + (size_t)(q2 * 16 + lrow) * P_ST + nt * 16 + g * 4) = w;
            }
        }
        f16x8 pa[2];
        #pragma unroll
        for (int q2 = 0; q2 < 2; ++q2) {
            const f16* pr = pls + (size_t)(q2 * 16 + lrow) * P_ST + g * 8;
            f16x4 lo = *(const f16x4*)pr;
            f16x4 hi = *(const f16x4*)(pr + 4);
            #pragma unroll
            for (int i = 0; i < 4; ++i) { pa[q2][i] = lo[i]; pa[q2][i + 4] = hi[i]; }
        }

        // ---- PV: acc[q 32][d 128] += P * V ----
        #pragma unroll
        for (int nd = 0; nd < 8; ++nd) {
            const f16* vr2 = vtr + (size_t)(nd * 16 + lrow) * VT_ST + g * 8;
            f16x8 bf = *(const f16x8*)vr2;
            #pragma unroll
            for (int q2 = 0; q2 < 2; ++q2)
                acc[q2][nd] = MFMA16(pa[q2], bf, acc[q2][nd]);
        }

        if (t + 1 < NTILES)
            stage_write((f16*)sba, (f16*)(sba + VH_BYTES), qw, lane, ld);
        __syncthreads();
    }

    // ---- cross-group merge via LDS slabs (smem repurposed; post-barrier) ----
    float* slab = (float*)smem;                       // [8 waves][32 q][SLAB_ST]
    float* mlp  = (float*)(smem + 8 * 32 * SLAB_ST * 4); // [8 waves][2][32]
    #pragma unroll
    for (int q2 = 0; q2 < 2; ++q2)
        #pragma unroll
        for (int nd = 0; nd < 8; ++nd)
            #pragma unroll
            for (int r = 0; r < 4; ++r)
                slab[(size_t)(wv * 32 + q2 * 16 + g * 4 + r) * SLAB_ST + nd * 16 + lrow] = acc[q2][nd][r];
    if (g == 0) {
        #pragma unroll
        for (int q2 = 0; q2 < 2; ++q2) {
            mlp[wv * 64 + q2 * 16 + lrow]      = m_run[q2];
            mlp[wv * 64 + 32 + q2 * 16 + lrow] = l_run[q2];
        }
    }
    __syncthreads();

    #pragma unroll
    for (int rr = 0; rr < 8; ++rr) {
        int row = wv * 8 + rr;              // 0..63 within block
        int qws = row >> 5, ql = row & 31;
        float mg[4], M = -3.0e38f;
        #pragma unroll
        for (int gg = 0; gg < 4; ++gg) {
            mg[gg] = mlp[(gg * 2 + qws) * 64 + ql];
            M = fmaxf(M, mg[gg]);
        }
        float L = 0.0f, f[4];
        #pragma unroll
        for (int gg = 0; gg < 4; ++gg) {
            f[gg] = __expf(mg[gg] - M);
            L += f[gg] * mlp[(gg * 2 + qws) * 64 + 32 + ql];
        }
        float inv = 1.0f / L;
        f32x2 o = { 0.0f, 0.0f };
        #pragma unroll
        for (int gg = 0; gg < 4; ++gg) {
            f32x2 v = *(const f32x2*)&slab[(size_t)((gg * 2 + qws) * 32 + ql) * SLAB_ST + lane * 2];
            o[0] += f[gg] * v[0];
            o[1] += f[gg] * v[1];
        }
        o[0] *= inv; o[1] *= inv;
        *(f32x2*)&Out[((size_t)b * L_DIM + q0 + row) * D_DIM + lane * 2] = o;
    }
}

extern "C" void kernel_launch(void* const* d_in, const int* in_sizes, int n_in,
                              void* d_out, int out_size, void* d_ws, size_t ws_size,
                              hipStream_t stream) {
    const float* Q = (const float*)d_in[0];
    const float* V = (const float*)d_in[1];
    float* Out     = (float*)d_out;
    attn_fwd<<<dim3(B_DIM * (L_DIM / 64)), dim3(512), 0, stream>>>(Q, V, Out);
}

// Round 5
// 45.589 us; speedup vs baseline: 2.4533x; 1.2947x over previous
//
#include <hip/hip_runtime.h>
#include <hip/hip_fp16.h>

typedef _Float16 f16;
typedef __attribute__((ext_vector_type(8))) _Float16 f16x8;
typedef __attribute__((ext_vector_type(4))) _Float16 f16x4;
typedef __attribute__((ext_vector_type(4))) short s16x4;
typedef __attribute__((ext_vector_type(4))) float f32x4;
typedef __attribute__((ext_vector_type(2))) float f32x2;

#define MFMA16(a,b,c) __builtin_amdgcn_mfma_f32_16x16x32_f16(a,b,c,0,0,0)

#define B_DIM 8
#define L_DIM 2048
#define D_DIM 128
#define NGRP 4
#define KVB 64
#define NTILES 8            // 512 kv per group / KVB
#define TILE_B 16384        // 64x128 f16, subtiled [kv4][d16][4][16]
#define P_ST 72             // P row stride (f16)
#define SLAB_ST 132
#define SMEM_B 137216       // max(4*2*16384 staging, 135168 slabs + 2048 ml)

__device__ __forceinline__ unsigned ldsa(const void* p) {
    return (unsigned)(unsigned long long)(const __attribute__((address_space(3))) char*)p;
}

#define TRRD(d, a, O) asm volatile("ds_read_b64_tr_b16 %0, %1 offset:" O : "=v"(d) : "v"(a))
#define LGKM0() do { asm volatile("s_waitcnt lgkmcnt(0)" ::: "memory"); __builtin_amdgcn_sched_barrier(0); } while (0)

#define PVND(TL, TH, PA0, PA1, ND) { \
    union { s16x4 s2[2]; f16x8 v; } uu; uu.s2[0] = TL; uu.s2[1] = TH; \
    acc[0][ND] = MFMA16(PA0, uu.v, acc[0][ND]); \
    acc[1][ND] = MFMA16(PA1, uu.v, acc[1][ND]); }

#define PV_HALF(AREG, PA0, PA1, S0,S0b,S1,S1b,S2,S2b,S3,S3b, NDB) { \
    s16x4 t0l,t0h,t1l,t1h,t2l,t2h,t3l,t3h; \
    TRRD(t0l, AREG, S0);  TRRD(t0h, AREG, S0b); \
    TRRD(t1l, AREG, S1);  TRRD(t1h, AREG, S1b); \
    TRRD(t2l, AREG, S2);  TRRD(t2h, AREG, S2b); \
    TRRD(t3l, AREG, S3);  TRRD(t3h, AREG, S3b); \
    LGKM0(); \
    PVND(t0l, t0h, PA0, PA1, NDB+0); PVND(t1l, t1h, PA0, PA1, NDB+1); \
    PVND(t2l, t2h, PA0, PA1, NDB+2); PVND(t3l, t3h, PA0, PA1, NDB+3); }

__global__ __launch_bounds__(512, 2) void attn_fwd(
    const float* __restrict__ Q, const float* __restrict__ V, float* __restrict__ Out)
{
    __shared__ __align__(16) char smem[SMEM_B];

    const int tid  = threadIdx.x;
    const int wv   = tid >> 6;
    const int grp  = wv >> 1;      // kv group 0..3 (512 kv each)
    const int qw   = wv & 1;       // q half (32 rows)
    const int lane = tid & 63;
    const int lrow = lane & 15;
    const int g    = lane >> 4;

    const int blk = blockIdx.x;
    const int b   = blk & 7;
    const int q0  = (blk >> 3) * 64;

    char* grpbase = smem + grp * (2 * TILE_B);

    // ---- Q fragments: fp16 hi/lo split ----
    f16x8 qhi[2][4], qlo[2][4];
    {
        const float* qb = Q + ((size_t)b * L_DIM + q0 + qw * 32) * D_DIM;
        #pragma unroll
        for (int q2 = 0; q2 < 2; ++q2) {
            const float* qp = qb + (size_t)(q2 * 16 + lrow) * D_DIM + g * 8;
            #pragma unroll
            for (int dt = 0; dt < 4; ++dt) {
                f32x4 f0 = *(const f32x4*)(qp + dt * 32);
                f32x4 f1 = *(const f32x4*)(qp + dt * 32 + 4);
                #pragma unroll
                for (int i = 0; i < 4; ++i) {
                    f16 h0 = (f16)f0[i];
                    qhi[q2][dt][i] = h0;
                    qlo[q2][dt][i] = (f16)(f0[i] - (float)h0);
                    f16 h1 = (f16)f1[i];
                    qhi[q2][dt][i + 4] = h1;
                    qlo[q2][dt][i + 4] = (f16)(f1[i] - (float)h1);
                }
            }
        }
    }

    f32x4 acc[2][8];
    #pragma unroll
    for (int q2 = 0; q2 < 2; ++q2)
        #pragma unroll
        for (int i = 0; i < 8; ++i) acc[q2][i] = (f32x4)0.0f;
    float m_run[2] = { -3.0e38f, -3.0e38f }, l_run[2] = { 0.0f, 0.0f };

    // lane-constant staging geometry
    const int kvl = qw * 32 + (lane >> 3);       // kv row base
    const int d4l = lane & 7;                    // d-quad base
    const int gl_off = kvl * D_DIM + d4l * 4;    // global float offset
    const int wbase = ((kvl >> 2) * 1024) + ((d4l >> 2) * 128) + (kvl & 3) * 32 + (d4l & 3) * 8;
    // QK A-frag lane offset (bytes within tile)
    const int qkoff = (lrow >> 2) * 1024 + (g >> 1) * 128 + (lrow & 3) * 32 + (g & 1) * 16;

    const float* vb = V + ((size_t)b * L_DIM + grp * (L_DIM / NGRP)) * D_DIM;

    // ---- prologue: stage tile 0 into buf0 ----
    {
        const float* vsrc = vb + gl_off;
        f32x4 ld0[16];
        #pragma unroll
        for (int ith = 0; ith < 4; ++ith)
            #pragma unroll
            for (int itd = 0; itd < 4; ++itd)
                ld0[ith * 4 + itd] = *(const f32x4*)(vsrc + ith * 1024 + itd * 32);
        #pragma unroll
        for (int ith = 0; ith < 4; ++ith)
            #pragma unroll
            for (int itd = 0; itd < 4; ++itd) {
                f32x4 f = ld0[ith * 4 + itd];
                f16x4 hv = { (f16)f[0], (f16)f[1], (f16)f[2], (f16)f[3] };
                *(f16x4*)(grpbase + wbase + ith * 2048 + itd * 256) = hv;
            }
    }
    __syncthreads();

    for (int t = 0; t < NTILES; ++t) {
        const int c = t & 1;
        char* cur = grpbase + c * TILE_B;
        char* alt = grpbase + (c ^ 1) * TILE_B;
        const bool hn = (t + 1 < NTILES);
        const float* vnext = vb + (size_t)(t + 1) * KVB * D_DIM + gl_off;

        f32x4 ldA[8], ldB[8];
        if (hn) {
            #pragma unroll
            for (int ith = 0; ith < 2; ++ith)
                #pragma unroll
                for (int itd = 0; itd < 4; ++itd)
                    ldA[ith * 4 + itd] = *(const f32x4*)(vnext + ith * 1024 + itd * 32);
        }

        // ---- QK^T swapped: S^T[kv 64][q 32], fp16 2-pass ----
        f32x4 s[2][4];
        #pragma unroll
        for (int q2 = 0; q2 < 2; ++q2)
            #pragma unroll
            for (int nt = 0; nt < 4; ++nt) s[q2][nt] = (f32x4)0.0f;
        #pragma unroll
        for (int nt = 0; nt < 4; ++nt) {
            #pragma unroll
            for (int dt = 0; dt < 4; ++dt) {
                f16x8 a = *(const f16x8*)(cur + qkoff + nt * 4096 + dt * 256);
                s[0][nt] = MFMA16(a, qhi[0][dt], s[0][nt]);
                s[0][nt] = MFMA16(a, qlo[0][dt], s[0][nt]);
                s[1][nt] = MFMA16(a, qhi[1][dt], s[1][nt]);
                s[1][nt] = MFMA16(a, qlo[1][dt], s[1][nt]);
            }
        }

        if (hn) {
            #pragma unroll
            for (int ith = 0; ith < 2; ++ith)
                #pragma unroll
                for (int itd = 0; itd < 4; ++itd)
                    ldB[ith * 4 + itd] = *(const f32x4*)(vnext + (ith + 2) * 1024 + itd * 32);
        }

        // ---- online softmax with defer-max (THR=8) ----
        float pm[2];
        #pragma unroll
        for (int q2 = 0; q2 < 2; ++q2) {
            float tm = s[q2][0][0];
            #pragma unroll
            for (int nt = 0; nt < 4; ++nt)
                #pragma unroll
                for (int r = 0; r < 4; ++r) tm = fmaxf(tm, s[q2][nt][r]);
            tm = fmaxf(tm, __shfl_xor(tm, 16));
            tm = fmaxf(tm, __shfl_xor(tm, 32));
            pm[q2] = tm;
        }
        bool need = (pm[0] > m_run[0] + 8.0f) || (pm[1] > m_run[1] + 8.0f);
        if (__any(need)) {
            float mnew[2], scl[2];
            #pragma unroll
            for (int q2 = 0; q2 < 2; ++q2) {
                mnew[q2] = fmaxf(m_run[q2], pm[q2]);
                scl[q2]  = __expf(m_run[q2] - mnew[q2]);
                m_run[q2] = mnew[q2];
                l_run[q2] *= scl[q2];
            }
            float sr[2][4];
            #pragma unroll
            for (int r = 0; r < 4; ++r) {
                sr[0][r] = __shfl(scl[0], g * 4 + r);
                sr[1][r] = __shfl(scl[1], g * 4 + r);
            }
            #pragma unroll
            for (int q2 = 0; q2 < 2; ++q2)
                #pragma unroll
                for (int nd = 0; nd < 8; ++nd)
                    #pragma unroll
                    for (int r = 0; r < 4; ++r) acc[q2][nd][r] *= sr[q2][r];
        }
        #pragma unroll
        for (int q2 = 0; q2 < 2; ++q2) {
            float ps = 0.0f;
            #pragma unroll
            for (int nt = 0; nt < 4; ++nt)
                #pragma unroll
                for (int r = 0; r < 4; ++r) {
                    float p = __expf(s[q2][nt][r] - m_run[q2]);
                    s[q2][nt][r] = p;
                    ps += p;
                }
            ps += __shfl_xor(ps, 16);
            ps += __shfl_xor(ps, 32);
            l_run[q2] += ps;
        }

        // ---- P -> LDS (dead half of alt buffer), read back as A-frags ----
        f16* pls = (f16*)(alt + qw * 8192);
        #pragma unroll
        for (int q2 = 0; q2 < 2; ++q2) {
            #pragma unroll
            for (int nt = 0; nt < 4; ++nt) {
                f16x4 w = { (f16)s[q2][nt][0], (f16)s[q2][nt][1],
                            (f16)s[q2][nt][2], (f16)s[q2][nt][3] };
                *(f16x4*)(pls + (size_t)(q2 * 16 + lrow) * P_ST + nt * 16 + g * 4) = w;
            }
        }
        f16x8 pa00, pa01, pa10, pa11;
        pa00 = *(const f16x8*)(pls + (size_t)(lrow) * P_ST + g * 8);
        pa01 = *(const f16x8*)(pls + (size_t)(lrow) * P_ST + 32 + g * 8);
        pa10 = *(const f16x8*)(pls + (size_t)(16 + lrow) * P_ST + g * 8);
        pa11 = *(const f16x8*)(pls + (size_t)(16 + lrow) * P_ST + 32 + g * 8);

        // batch-1 stage writes (kv rows qw*32+0..15; P already consumed)
        if (hn) {
            #pragma unroll
            for (int ith = 0; ith < 2; ++ith)
                #pragma unroll
                for (int itd = 0; itd < 4; ++itd) {
                    f32x4 f = ldA[ith * 4 + itd];
                    f16x4 hv = { (f16)f[0], (f16)f[1], (f16)f[2], (f16)f[3] };
                    *(f16x4*)(alt + wbase + ith * 2048 + itd * 256) = hv;
                }
        }

        // ---- PV via hardware transpose reads ----
        // subtile (kvb = 8*kk + 2*g, db = nd) base = kk*8192 + g*2048 + nd*128;
        // per-lane own-chunk offset = (lane&15)*8 bytes; second kv sub-block = +1024.
        unsigned atr0 = ldsa(cur) + (unsigned)(g * 2048 + lrow * 8);
        unsigned atr1 = atr0 + 8192u;
        PV_HALF(atr0, pa00, pa10, "0","1024","128","1152","256","1280","384","1408", 0);
        PV_HALF(atr0, pa00, pa10, "512","1536","640","1664","768","1792","896","1920", 4);
        PV_HALF(atr1, pa01, pa11, "0","1024","128","1152","256","1280","384","1408", 0);
        PV_HALF(atr1, pa01, pa11, "512","1536","640","1664","768","1792","896","1920", 4);

        if (hn) {
            #pragma unroll
            for (int ith = 0; ith < 2; ++ith)
                #pragma unroll
                for (int itd = 0; itd < 4; ++itd) {
                    f32x4 f = ldB[ith * 4 + itd];
                    f16x4 hv = { (f16)f[0], (f16)f[1], (f16)f[2], (f16)f[3] };
                    *(f16x4*)(alt + wbase + (ith + 2) * 2048 + itd * 256) = hv;
                }
        }
        __syncthreads();
    }

    // ---- cross-group merge (smem repurposed after final barrier) ----
    float* slab = (float*)smem;                          // [8 waves][32 q][SLAB_ST]
    float* mlp  = (float*)(smem + 8 * 32 * SLAB_ST * 4); // [8 waves][2][32]
    #pragma unroll
    for (int q2 = 0; q2 < 2; ++q2)
        #pragma unroll
        for (int nd = 0; nd < 8; ++nd)
            #pragma unroll
            for (int r = 0; r < 4; ++r)
                slab[(size_t)(wv * 32 + q2 * 16 + g * 4 + r) * SLAB_ST + nd * 16 + lrow] = acc[q2][nd][r];
    if (g == 0) {
        #pragma unroll
        for (int q2 = 0; q2 < 2; ++q2) {
            mlp[wv * 64 + q2 * 16 + lrow]      = m_run[q2];
            mlp[wv * 64 + 32 + q2 * 16 + lrow] = l_run[q2];
        }
    }
    __syncthreads();

    #pragma unroll
    for (int rr = 0; rr < 8; ++rr) {
        int row = wv * 8 + rr;
        int qws = row >> 5, ql = row & 31;
        float mg[4], M = -3.0e38f;
        #pragma unroll
        for (int gg = 0; gg < 4; ++gg) {
            mg[gg] = mlp[(gg * 2 + qws) * 64 + ql];
            M = fmaxf(M, mg[gg]);
        }
        float L = 0.0f, f[4];
        #pragma unroll
        for (int gg = 0; gg < 4; ++gg) {
            f[gg] = __expf(mg[gg] - M);
            L += f[gg] * mlp[(gg * 2 + qws) * 64 + 32 + ql];
        }
        float inv = 1.0f / L;
        f32x2 o = { 0.0f, 0.0f };
        #pragma unroll
        for (int gg = 0; gg < 4; ++gg) {
            f32x2 v = *(const f32x2*)&slab[(size_t)((gg * 2 + qws) * 32 + ql) * SLAB_ST + lane * 2];
            o[0] += f[gg] * v[0];
            o[1] += f[gg] * v[1];
        }
        o[0] *= inv; o[1] *= inv;
        *(f32x2*)&Out[((size_t)b * L_DIM + q0 + row) * D_DIM + lane * 2] = o;
    }
}

extern "C" void kernel_launch(void* const* d_in, const int* in_sizes, int n_in,
                              void* d_out, int out_size, void* d_ws, size_t ws_size,
                              hipStream_t stream) {
    const float* Q = (const float*)d_in[0];
    const float* V = (const float*)d_in[1];
    float* Out     = (float*)d_out;
    attn_fwd<<<dim3(B_DIM * (L_DIM / 64)), dim3(512), 0, stream>>>(Q, V, Out);
}

// Round 6
// 45.084 us; speedup vs baseline: 2.4807x; 1.0112x over previous
//
#include <hip/hip_runtime.h>
#include <hip/hip_fp16.h>

typedef _Float16 f16;
typedef __attribute__((ext_vector_type(8))) _Float16 f16x8;
typedef __attribute__((ext_vector_type(4))) _Float16 f16x4;
typedef __attribute__((ext_vector_type(4))) short s16x4;
typedef __attribute__((ext_vector_type(4))) float f32x4;
typedef __attribute__((ext_vector_type(2))) float f32x2;

#define MFMA16(a,b,c) __builtin_amdgcn_mfma_f32_16x16x32_f16(a,b,c,0,0,0)
#define EXP2(x) __builtin_amdgcn_exp2f(x)
#define LOG2E 1.4426950408889634f

#define B_DIM 8
#define L_DIM 2048
#define D_DIM 128
#define NGRP 4
#define KVB 64
#define NTILES 8             // 512 kv per group / KVB
#define BLKB 1040            // kv4-block stride: 1024 + 16B pad (bank-phase rotate)
#define TILE_B (16 * BLKB)   // 16640
#define P_ST 72              // P row stride (f16)
#define SLAB_ST 132
#define SMEM_B 137216        // max(4*2*16640=133120 staging, 135168 slabs + 2048 ml)

__device__ __forceinline__ unsigned ldsa(const void* p) {
    return (unsigned)(unsigned long long)(const __attribute__((address_space(3))) char*)p;
}

#define TRRD(d, a, O) asm volatile("ds_read_b64_tr_b16 %0, %1 offset:" O : "=v"(d) : "v"(a))
#define LGKM0() do { asm volatile("s_waitcnt lgkmcnt(0)" ::: "memory"); __builtin_amdgcn_sched_barrier(0); } while (0)

#define PVND(TL, TH, PA0, PA1, ND) { \
    union { s16x4 s2[2]; f16x8 v; } uu; uu.s2[0] = TL; uu.s2[1] = TH; \
    acc[0][ND] = MFMA16(PA0, uu.v, acc[0][ND]); \
    acc[1][ND] = MFMA16(PA1, uu.v, acc[1][ND]); }

#define PV_HALF(AREG, PA0, PA1, S0,S0b,S1,S1b,S2,S2b,S3,S3b, NDB) { \
    s16x4 t0l,t0h,t1l,t1h,t2l,t2h,t3l,t3h; \
    TRRD(t0l, AREG, S0);  TRRD(t0h, AREG, S0b); \
    TRRD(t1l, AREG, S1);  TRRD(t1h, AREG, S1b); \
    TRRD(t2l, AREG, S2);  TRRD(t2h, AREG, S2b); \
    TRRD(t3l, AREG, S3);  TRRD(t3h, AREG, S3b); \
    LGKM0(); \
    __builtin_amdgcn_s_setprio(1); \
    PVND(t0l, t0h, PA0, PA1, NDB+0); PVND(t1l, t1h, PA0, PA1, NDB+1); \
    PVND(t2l, t2h, PA0, PA1, NDB+2); PVND(t3l, t3h, PA0, PA1, NDB+3); \
    __builtin_amdgcn_s_setprio(0); }

__global__ __launch_bounds__(512, 2) void attn_fwd(
    const float* __restrict__ Q, const float* __restrict__ V, float* __restrict__ Out)
{
    __shared__ __align__(16) char smem[SMEM_B];

    const int tid  = threadIdx.x;
    const int wv   = tid >> 6;
    const int grp  = wv >> 1;      // kv group 0..3 (512 kv each)
    const int qw   = wv & 1;       // q half (32 rows)
    const int lane = tid & 63;
    const int lrow = lane & 15;
    const int g    = lane >> 4;

    const int blk = blockIdx.x;
    const int b   = blk & 7;
    const int q0  = (blk >> 3) * 64;

    char* grpbase = smem + grp * (2 * TILE_B);

    // ---- Q fragments: fp16 hi/lo split, pre-scaled by log2(e) ----
    f16x8 qhi[2][4], qlo[2][4];
    {
        const float* qb = Q + ((size_t)b * L_DIM + q0 + qw * 32) * D_DIM;
        #pragma unroll
        for (int q2 = 0; q2 < 2; ++q2) {
            const float* qp = qb + (size_t)(q2 * 16 + lrow) * D_DIM + g * 8;
            #pragma unroll
            for (int dt = 0; dt < 4; ++dt) {
                f32x4 f0 = *(const f32x4*)(qp + dt * 32);
                f32x4 f1 = *(const f32x4*)(qp + dt * 32 + 4);
                #pragma unroll
                for (int i = 0; i < 4; ++i) {
                    float s0 = f0[i] * LOG2E;
                    f16 h0 = (f16)s0;
                    qhi[q2][dt][i] = h0;
                    qlo[q2][dt][i] = (f16)(s0 - (float)h0);
                    float s1 = f1[i] * LOG2E;
                    f16 h1 = (f16)s1;
                    qhi[q2][dt][i + 4] = h1;
                    qlo[q2][dt][i + 4] = (f16)(s1 - (float)h1);
                }
            }
        }
    }

    f32x4 acc[2][8];
    #pragma unroll
    for (int q2 = 0; q2 < 2; ++q2)
        #pragma unroll
        for (int i = 0; i < 8; ++i) acc[q2][i] = (f32x4)0.0f;
    float m_run[2] = { -3.0e38f, -3.0e38f }, l_run[2] = { 0.0f, 0.0f };

    // lane-constant staging geometry
    const int kvl = qw * 32 + (lane >> 3);       // kv row base
    const int d4l = lane & 7;                    // d-quad base
    const int gl_off = kvl * D_DIM + d4l * 4;    // global float offset
    const int wbase = ((kvl >> 2) * BLKB) + ((d4l >> 2) * 128) + (kvl & 3) * 32 + (d4l & 3) * 8;
    // QK A-frag lane offset (bytes within tile)
    const int qkoff = (lrow >> 2) * BLKB + (g >> 1) * 128 + (lrow & 3) * 32 + (g & 1) * 16;

    const float* vb = V + ((size_t)b * L_DIM + grp * (L_DIM / NGRP)) * D_DIM;

    // ---- prologue: stage tile 0 into buf0 ----
    {
        const float* vsrc = vb + gl_off;
        f32x4 ld0[16];
        #pragma unroll
        for (int ith = 0; ith < 4; ++ith)
            #pragma unroll
            for (int itd = 0; itd < 4; ++itd)
                ld0[ith * 4 + itd] = *(const f32x4*)(vsrc + ith * 1024 + itd * 32);
        #pragma unroll
        for (int ith = 0; ith < 4; ++ith)
            #pragma unroll
            for (int itd = 0; itd < 4; ++itd) {
                f32x4 f = ld0[ith * 4 + itd];
                f16x4 hv = { (f16)f[0], (f16)f[1], (f16)f[2], (f16)f[3] };
                *(f16x4*)(grpbase + wbase + ith * (2 * BLKB) + itd * 256) = hv;
            }
    }
    __syncthreads();

    for (int t = 0; t < NTILES; ++t) {
        const int c = t & 1;
        char* cur = grpbase + c * TILE_B;
        char* alt = grpbase + (c ^ 1) * TILE_B;
        const bool hn = (t + 1 < NTILES);
        const float* vnext = vb + (size_t)(t + 1) * KVB * D_DIM + gl_off;

        f32x4 ldA[8], ldB[8];
        if (hn) {
            #pragma unroll
            for (int ith = 0; ith < 2; ++ith)
                #pragma unroll
                for (int itd = 0; itd < 4; ++itd)
                    ldA[ith * 4 + itd] = *(const f32x4*)(vnext + ith * 1024 + itd * 32);
        }

        // ---- QK^T swapped: S^T[kv 64][q 32], fp16 2-pass (log2e-scaled) ----
        f32x4 s[2][4];
        #pragma unroll
        for (int q2 = 0; q2 < 2; ++q2)
            #pragma unroll
            for (int nt = 0; nt < 4; ++nt) s[q2][nt] = (f32x4)0.0f;
        __builtin_amdgcn_s_setprio(1);
        #pragma unroll
        for (int nt = 0; nt < 4; ++nt) {
            #pragma unroll
            for (int dt = 0; dt < 4; ++dt) {
                f16x8 a = *(const f16x8*)(cur + qkoff + nt * (4 * BLKB) + dt * 256);
                s[0][nt] = MFMA16(a, qhi[0][dt], s[0][nt]);
                s[0][nt] = MFMA16(a, qlo[0][dt], s[0][nt]);
                s[1][nt] = MFMA16(a, qhi[1][dt], s[1][nt]);
                s[1][nt] = MFMA16(a, qlo[1][dt], s[1][nt]);
            }
        }
        __builtin_amdgcn_s_setprio(0);

        if (hn) {
            #pragma unroll
            for (int ith = 0; ith < 2; ++ith)
                #pragma unroll
                for (int itd = 0; itd < 4; ++itd)
                    ldB[ith * 4 + itd] = *(const f32x4*)(vnext + (ith + 2) * 1024 + itd * 32);
        }

        // ---- online softmax with defer-max (THR=8 nats = 11.5 log2) ----
        float pm[2];
        #pragma unroll
        for (int q2 = 0; q2 < 2; ++q2) {
            float tm = s[q2][0][0];
            #pragma unroll
            for (int nt = 0; nt < 4; ++nt)
                #pragma unroll
                for (int r = 0; r < 4; ++r) tm = fmaxf(tm, s[q2][nt][r]);
            tm = fmaxf(tm, __shfl_xor(tm, 16));
            tm = fmaxf(tm, __shfl_xor(tm, 32));
            pm[q2] = tm;
        }
        bool need = (pm[0] > m_run[0] + 11.5f) || (pm[1] > m_run[1] + 11.5f);
        if (__any(need)) {
            float scl[2];
            #pragma unroll
            for (int q2 = 0; q2 < 2; ++q2) {
                float mnew = fmaxf(m_run[q2], pm[q2]);
                scl[q2]  = EXP2(m_run[q2] - mnew);
                m_run[q2] = mnew;
                l_run[q2] *= scl[q2];
            }
            float sr[2][4];
            #pragma unroll
            for (int r = 0; r < 4; ++r) {
                sr[0][r] = __shfl(scl[0], g * 4 + r);
                sr[1][r] = __shfl(scl[1], g * 4 + r);
            }
            #pragma unroll
            for (int q2 = 0; q2 < 2; ++q2)
                #pragma unroll
                for (int nd = 0; nd < 8; ++nd)
                    #pragma unroll
                    for (int r = 0; r < 4; ++r) acc[q2][nd][r] *= sr[q2][r];
        }
        #pragma unroll
        for (int q2 = 0; q2 < 2; ++q2) {
            float ps = 0.0f;
            #pragma unroll
            for (int nt = 0; nt < 4; ++nt)
                #pragma unroll
                for (int r = 0; r < 4; ++r) {
                    float p = EXP2(s[q2][nt][r] - m_run[q2]);
                    s[q2][nt][r] = p;
                    ps += p;
                }
            ps += __shfl_xor(ps, 16);
            ps += __shfl_xor(ps, 32);
            l_run[q2] += ps;
        }

        // ---- P -> LDS (dead half of alt buffer: own qw's stage region), read back as A-frags ----
        f16* pls = (f16*)(alt + qw * (8 * BLKB));
        #pragma unroll
        for (int q2 = 0; q2 < 2; ++q2) {
            #pragma unroll
            for (int nt = 0; nt < 4; ++nt) {
                f16x4 w = { (f16)s[q2][nt][0], (f16)s[q2][nt][1],
                            (f16)s[q2][nt][2], (f16)s[q2][nt][3] };
                *(f16x4*)(pls + (size_t)(q2 * 16 + lrow) * P_ST + nt * 16 + g * 4) = w;
            }
        }
        f16x8 pa00, pa01, pa10, pa11;
        pa00 = *(const f16x8*)(pls + (size_t)(lrow) * P_ST + g * 8);
        pa01 = *(const f16x8*)(pls + (size_t)(lrow) * P_ST + 32 + g * 8);
        pa10 = *(const f16x8*)(pls + (size_t)(16 + lrow) * P_ST + g * 8);
        pa11 = *(const f16x8*)(pls + (size_t)(16 + lrow) * P_ST + 32 + g * 8);

        // batch-1 stage writes (own qw stage region; P already consumed)
        if (hn) {
            #pragma unroll
            for (int ith = 0; ith < 2; ++ith)
                #pragma unroll
                for (int itd = 0; itd < 4; ++itd) {
                    f32x4 f = ldA[ith * 4 + itd];
                    f16x4 hv = { (f16)f[0], (f16)f[1], (f16)f[2], (f16)f[3] };
                    *(f16x4*)(alt + wbase + ith * (2 * BLKB) + itd * 256) = hv;
                }
        }

        // ---- PV via hardware transpose reads (bank-phase-rotated blocks) ----
        // subtile (kv4-block = 8*kk + 2*g) base = kk*8*BLKB + g*2*BLKB + nd*128;
        // per-lane own-chunk offset = (lane&15)*8 bytes; next kv4-block = +BLKB.
        unsigned atr0 = ldsa(cur) + (unsigned)(g * (2 * BLKB) + lrow * 8);
        unsigned atr1 = atr0 + (unsigned)(8 * BLKB);
        PV_HALF(atr0, pa00, pa10, "0","1040","128","1168","256","1296","384","1424", 0);
        PV_HALF(atr0, pa00, pa10, "512","1552","640","1680","768","1808","896","1936", 4);
        PV_HALF(atr1, pa01, pa11, "0","1040","128","1168","256","1296","384","1424", 0);
        PV_HALF(atr1, pa01, pa11, "512","1552","640","1680","768","1808","896","1936", 4);

        if (hn) {
            #pragma unroll
            for (int ith = 0; ith < 2; ++ith)
                #pragma unroll
                for (int itd = 0; itd < 4; ++itd) {
                    f32x4 f = ldB[ith * 4 + itd];
                    f16x4 hv = { (f16)f[0], (f16)f[1], (f16)f[2], (f16)f[3] };
                    *(f16x4*)(alt + wbase + (ith + 2) * (2 * BLKB) + itd * 256) = hv;
                }
        }
        __syncthreads();
    }

    // ---- cross-group merge (smem repurposed after final barrier) ----
    float* slab = (float*)smem;                          // [8 waves][32 q][SLAB_ST]
    float* mlp  = (float*)(smem + 8 * 32 * SLAB_ST * 4); // [8 waves][2][32]
    #pragma unroll
    for (int q2 = 0; q2 < 2; ++q2)
        #pragma unroll
        for (int nd = 0; nd < 8; ++nd)
            #pragma unroll
            for (int r = 0; r < 4; ++r)
                slab[(size_t)(wv * 32 + q2 * 16 + g * 4 + r) * SLAB_ST + nd * 16 + lrow] = acc[q2][nd][r];
    if (g == 0) {
        #pragma unroll
        for (int q2 = 0; q2 < 2; ++q2) {
            mlp[wv * 64 + q2 * 16 + lrow]      = m_run[q2];
            mlp[wv * 64 + 32 + q2 * 16 + lrow] = l_run[q2];
        }
    }
    __syncthreads();

    #pragma unroll
    for (int rr = 0; rr < 8; ++rr) {
        int row = wv * 8 + rr;
        int qws = row >> 5, ql = row & 31;
        float mg[4], M = -3.0e38f;
        #pragma unroll
        for (int gg = 0; gg < 4; ++gg) {
            mg[gg] = mlp[(gg * 2 + qws) * 64 + ql];
            M = fmaxf(M, mg[gg]);
        }
        float L = 0.0f, f[4];
        #pragma unroll
        for (int gg = 0; gg < 4; ++gg) {
            f[gg] = EXP2(mg[gg] - M);
            L += f[gg] * mlp[(gg * 2 + qws) * 64 + 32 + ql];
        }
        float inv = 1.0f / L;
        f32x2 o = { 0.0f, 0.0f };
        #pragma unroll
        for (int gg = 0; gg < 4; ++gg) {
            f32x2 v = *(const f32x2*)&slab[(size_t)((gg * 2 + qws) * 32 + ql) * SLAB_ST + lane * 2];
            o[0] += f[gg] * v[0];
            o[1] += f[gg] * v[1];
        }
        o[0] *= inv; o[1] *= inv;
        *(f32x2*)&Out[((size_t)b * L_DIM + q0 + row) * D_DIM + lane * 2] = o;
    }
}

extern "C" void kernel_launch(void* const* d_in, const int* in_sizes, int n_in,
                              void* d_out, int out_size, void* d_ws, size_t ws_size,
                              hipStream_t stream) {
    const float* Q = (const float*)d_in[0];
    const float* V = (const float*)d_in[1];
    float* Out     = (float*)d_out;
    attn_fwd<<<dim3(B_DIM * (L_DIM / 64)), dim3(512), 0, stream>>>(Q, V, Out);
}

// Round 8
// 41.393 us; speedup vs baseline: 2.7020x; 1.0892x over previous
//
#include <hip/hip_runtime.h>
#include <hip/hip_fp16.h>

typedef _Float16 f16;
typedef __attribute__((ext_vector_type(8))) _Float16 f16x8;
typedef __attribute__((ext_vector_type(4))) _Float16 f16x4;
typedef __attribute__((ext_vector_type(4))) short s16x4;
typedef __attribute__((ext_vector_type(4))) float f32x4;
typedef __attribute__((ext_vector_type(2))) float f32x2;

#define MFMA16(a,b,c) __builtin_amdgcn_mfma_f32_16x16x32_f16(a,b,c,0,0,0)
#define EXP2(x) __builtin_amdgcn_exp2f(x)
#define LOG2E 1.4426950408889634f

#define B_DIM 8
#define L_DIM 2048
#define D_DIM 128
#define NGRP 4
#define KVB 64
#define NTILES 8             // 512 kv per group / KVB
#define TILE_B 16384         // 64x128 f16, subtiled [kv4][d16][kv&3][16B-chunks]
#define P_ST 72              // P row stride (f16)
#define SLAB_ST 132
#define SMEM_B 137216        // staging 4*2*16384=131072; epilogue slabs 135168+2048

__device__ __forceinline__ unsigned ldsa(const void* p) {
    return (unsigned)(unsigned long long)(const __attribute__((address_space(3))) char*)p;
}

#define TRRD(d, a, O) asm volatile("ds_read_b64_tr_b16 %0, %1 offset:" O : "=v"(d) : "v"(a))
#define LGKM0() do { asm volatile("s_waitcnt lgkmcnt(0)" ::: "memory"); __builtin_amdgcn_sched_barrier(0); } while (0)
#define GLDS(gp, lp) __builtin_amdgcn_global_load_lds( \
    (const __attribute__((address_space(1))) unsigned int*)(gp), \
    (__attribute__((address_space(3))) unsigned int*)(lp), 16, 0, 0)

#define PVND(TL, TH, PA0, PA1, ND) { \
    union { s16x4 s2[2]; f16x8 v; } uu; uu.s2[0] = TL; uu.s2[1] = TH; \
    acc[0][ND] = MFMA16(PA0, uu.v, acc[0][ND]); \
    acc[1][ND] = MFMA16(PA1, uu.v, acc[1][ND]); }

#define PV_HALF(AREG, PA0, PA1, S0,S0b,S1,S1b,S2,S2b,S3,S3b, NDB) { \
    s16x4 t0l,t0h,t1l,t1h,t2l,t2h,t3l,t3h; \
    TRRD(t0l, AREG, S0);  TRRD(t0h, AREG, S0b); \
    TRRD(t1l, AREG, S1);  TRRD(t1h, AREG, S1b); \
    TRRD(t2l, AREG, S2);  TRRD(t2h, AREG, S2b); \
    TRRD(t3l, AREG, S3);  TRRD(t3h, AREG, S3b); \
    LGKM0(); \
    __builtin_amdgcn_s_setprio(1); \
    PVND(t0l, t0h, PA0, PA1, NDB+0); PVND(t1l, t1h, PA0, PA1, NDB+1); \
    PVND(t2l, t2h, PA0, PA1, NDB+2); PVND(t3l, t3h, PA0, PA1, NDB+3); \
    __builtin_amdgcn_s_setprio(0); }

// ---- pre-pass: V f32 -> f16 in chunk-permuted subtile order, one block per 64-kv tile ----
__global__ __launch_bounds__(256) void prep_v(const float* __restrict__ V, f16* __restrict__ ws) {
    const int blk = blockIdx.x;                    // b*32 + tt
    const float* src = V + (size_t)blk * (KVB * D_DIM);
    f16* dst = ws + (size_t)blk * (KVB * D_DIM);
    const int t = threadIdx.x;
    #pragma unroll
    for (int ii = 0; ii < 4; ++ii) {
        int lin = ii * 256 + t;
        int kv = lin >> 4, oct = lin & 15;         // oct = d/8
        const float* sp = src + kv * D_DIM + oct * 8;
        f32x4 a = *(const f32x4*)sp;
        f32x4 b = *(const f32x4*)(sp + 4);
        // chunk id for (kv, d0=oct*8): offset/16 = (kv>>2)*64 + (d0>>4)*8 + (kv&3)*2 + ((d0>>3)&1)
        int c = (kv >> 2) * 64 + (oct >> 1) * 8 + (kv & 3) * 2 + (oct & 1);
        union { f16 h[8]; f16x8 v; } u;
        #pragma unroll
        for (int k = 0; k < 4; ++k) { u.h[k] = (f16)a[k]; u.h[k + 4] = (f16)b[k]; }
        *(f16x8*)(dst + (size_t)c * 8) = u.v;
    }
}

__global__ __launch_bounds__(512, 2) void attn_fwd(
    const float* __restrict__ Q, const f16* __restrict__ ws, float* __restrict__ Out)
{
    __shared__ __align__(16) char smem[SMEM_B];

    const int tid  = threadIdx.x;
    const int wv   = tid >> 6;
    const int grp  = wv >> 1;      // kv group 0..3 (512 kv each)
    const int qw   = wv & 1;       // q half (32 rows)
    const int lane = tid & 63;
    const int lrow = lane & 15;
    const int g    = lane >> 4;

    const int blk = blockIdx.x;
    const int b   = blk & 7;
    const int q0  = (blk >> 3) * 64;

    char* grpbase = smem + grp * (2 * TILE_B);

    // ---- Q fragments: fp16 hi/lo split, pre-scaled by log2(e) ----
    f16x8 qhi[2][4], qlo[2][4];
    {
        const float* qb = Q + ((size_t)b * L_DIM + q0 + qw * 32) * D_DIM;
        #pragma unroll
        for (int q2 = 0; q2 < 2; ++q2) {
            const float* qp = qb + (size_t)(q2 * 16 + lrow) * D_DIM + g * 8;
            #pragma unroll
            for (int dt = 0; dt < 4; ++dt) {
                f32x4 f0 = *(const f32x4*)(qp + dt * 32);
                f32x4 f1 = *(const f32x4*)(qp + dt * 32 + 4);
                #pragma unroll
                for (int i = 0; i < 4; ++i) {
                    float s0 = f0[i] * LOG2E;
                    f16 h0 = (f16)s0;
                    qhi[q2][dt][i] = h0;
                    qlo[q2][dt][i] = (f16)(s0 - (float)h0);
                    float s1 = f1[i] * LOG2E;
                    f16 h1 = (f16)s1;
                    qhi[q2][dt][i + 4] = h1;
                    qlo[q2][dt][i + 4] = (f16)(s1 - (float)h1);
                }
            }
        }
    }

    f32x4 acc[2][8];
    #pragma unroll
    for (int q2 = 0; q2 < 2; ++q2)
        #pragma unroll
        for (int i = 0; i < 8; ++i) acc[q2][i] = (f32x4)0.0f;
    float m_run[2] = { -3.0e38f, -3.0e38f }, l_run[2] = { 0.0f, 0.0f };

    // QK A-frag lane offset (bytes within tile)
    const int qkoff = (lrow >> 2) * 1024 + (g >> 1) * 128 + (lrow & 3) * 32 + (g & 1) * 16;

    const f16* wsb = ws + (size_t)b * (32 * KVB * D_DIM);   // this batch's ws slice

    // ---- prologue: DMA tile 0 into buf0 ----
    {
        const f16* w0 = wsb + (size_t)(grp * 8) * 8192 + (size_t)(qw * 512 + lane) * 8;
        char* ldst = grpbase + qw * 8192;
        #pragma unroll
        for (int i = 0; i < 8; ++i) GLDS(w0 + i * 512, ldst + i * 1024);
    }
    __syncthreads();

    for (int t = 0; t < NTILES; ++t) {
        const int c = t & 1;
        char* cur = grpbase + c * TILE_B;
        char* alt = grpbase + (c ^ 1) * TILE_B;

        // ---- QK^T swapped: S^T[kv 64][q 32], fp16 2-pass (log2e-scaled) ----
        f32x4 s[2][4];
        #pragma unroll
        for (int q2 = 0; q2 < 2; ++q2)
            #pragma unroll
            for (int nt = 0; nt < 4; ++nt) s[q2][nt] = (f32x4)0.0f;
        __builtin_amdgcn_s_setprio(1);
        #pragma unroll
        for (int nt = 0; nt < 4; ++nt) {
            #pragma unroll
            for (int dt = 0; dt < 4; ++dt) {
                f16x8 a = *(const f16x8*)(cur + qkoff + nt * 4096 + dt * 256);
                s[0][nt] = MFMA16(a, qhi[0][dt], s[0][nt]);
                s[0][nt] = MFMA16(a, qlo[0][dt], s[0][nt]);
                s[1][nt] = MFMA16(a, qhi[1][dt], s[1][nt]);
                s[1][nt] = MFMA16(a, qlo[1][dt], s[1][nt]);
            }
        }
        __builtin_amdgcn_s_setprio(0);

        // ---- online softmax with defer-max (THR=11.5 in log2 units) ----
        float pm[2];
        #pragma unroll
        for (int q2 = 0; q2 < 2; ++q2) {
            float tm = s[q2][0][0];
            #pragma unroll
            for (int nt = 0; nt < 4; ++nt)
                #pragma unroll
                for (int r = 0; r < 4; ++r) tm = fmaxf(tm, s[q2][nt][r]);
            tm = fmaxf(tm, __shfl_xor(tm, 16));
            tm = fmaxf(tm, __shfl_xor(tm, 32));
            pm[q2] = tm;
        }
        bool need = (pm[0] > m_run[0] + 11.5f) || (pm[1] > m_run[1] + 11.5f);
        if (__any(need)) {
            float scl[2];
            #pragma unroll
            for (int q2 = 0; q2 < 2; ++q2) {
                float mnew = fmaxf(m_run[q2], pm[q2]);
                scl[q2]  = EXP2(m_run[q2] - mnew);
                m_run[q2] = mnew;
                l_run[q2] *= scl[q2];
            }
            float sr[2][4];
            #pragma unroll
            for (int r = 0; r < 4; ++r) {
                sr[0][r] = __shfl(scl[0], g * 4 + r);
                sr[1][r] = __shfl(scl[1], g * 4 + r);
            }
            #pragma unroll
            for (int q2 = 0; q2 < 2; ++q2)
                #pragma unroll
                for (int nd = 0; nd < 8; ++nd)
                    #pragma unroll
                    for (int r = 0; r < 4; ++r) acc[q2][nd][r] *= sr[q2][r];
        }
        #pragma unroll
        for (int q2 = 0; q2 < 2; ++q2) {
            float ps = 0.0f;
            #pragma unroll
            for (int nt = 0; nt < 4; ++nt)
                #pragma unroll
                for (int r = 0; r < 4; ++r) {
                    float p = EXP2(s[q2][nt][r] - m_run[q2]);
                    s[q2][nt][r] = p;
                    ps += p;
                }
            ps += __shfl_xor(ps, 16);
            ps += __shfl_xor(ps, 32);
            l_run[q2] += ps;
        }

        // ---- P -> LDS (dead half of alt buffer), read back as A-frags ----
        f16* pls = (f16*)(alt + qw * 8192);
        #pragma unroll
        for (int q2 = 0; q2 < 2; ++q2) {
            #pragma unroll
            for (int nt = 0; nt < 4; ++nt) {
                f16x4 w = { (f16)s[q2][nt][0], (f16)s[q2][nt][1],
                            (f16)s[q2][nt][2], (f16)s[q2][nt][3] };
                *(f16x4*)(pls + (size_t)(q2 * 16 + lrow) * P_ST + nt * 16 + g * 4) = w;
            }
        }
        f16x8 pa00, pa01, pa10, pa11;
        pa00 = *(const f16x8*)(pls + (size_t)(lrow) * P_ST + g * 8);
        pa01 = *(const f16x8*)(pls + (size_t)(lrow) * P_ST + 32 + g * 8);
        pa10 = *(const f16x8*)(pls + (size_t)(16 + lrow) * P_ST + g * 8);
        pa11 = *(const f16x8*)(pls + (size_t)(16 + lrow) * P_ST + 32 + g * 8);
        LGKM0();   // P reads landed in regs -> safe to DMA-overwrite the slice

        // ---- issue DMA staging of tile t+1 into alt (stays in flight under PV) ----
        if (t + 1 < NTILES) {
            const f16* wnt = wsb + (size_t)(grp * 8 + t + 1) * 8192 + (size_t)(qw * 512 + lane) * 8;
            char* ldst = alt + qw * 8192;
            #pragma unroll
            for (int i = 0; i < 8; ++i) GLDS(wnt + i * 512, ldst + i * 1024);
        }

        // ---- PV via hardware transpose reads ----
        // subtile (kv4-block = 8*kk + 2*g) base = kk*8192 + g*2048 + nd*128;
        // per-lane own-chunk offset = (lane&15)*8 bytes; second kv sub-block = +1024.
        unsigned atr0 = ldsa(cur) + (unsigned)(g * 2048 + lrow * 8);
        unsigned atr1 = atr0 + 8192u;
        PV_HALF(atr0, pa00, pa10, "0","1024","128","1152","256","1280","384","1408", 0);
        PV_HALF(atr0, pa00, pa10, "512","1536","640","1664","768","1792","896","1920", 4);
        PV_HALF(atr1, pa01, pa11, "0","1024","128","1152","256","1280","384","1408", 0);
        PV_HALF(atr1, pa01, pa11, "512","1536","640","1664","768","1792","896","1920", 4);

        __syncthreads();   // drains vmcnt (DMA) + lgkm; next iter reads alt
    }

    // ---- cross-group merge (smem repurposed after final barrier) ----
    float* slab = (float*)smem;                          // [8 waves][32 q][SLAB_ST]
    float* mlp  = (float*)(smem + 8 * 32 * SLAB_ST * 4); // [8 waves][2][32]
    #pragma unroll
    for (int q2 = 0; q2 < 2; ++q2)
        #pragma unroll
        for (int nd = 0; nd < 8; ++nd)
            #pragma unroll
            for (int r = 0; r < 4; ++r)
                slab[(size_t)(wv * 32 + q2 * 16 + g * 4 + r) * SLAB_ST + nd * 16 + lrow] = acc[q2][nd][r];
    if (g == 0) {
        #pragma unroll
        for (int q2 = 0; q2 < 2; ++q2) {
            mlp[wv * 64 + q2 * 16 + lrow]      = m_run[q2];
            mlp[wv * 64 + 32 + q2 * 16 + lrow] = l_run[q2];
        }
    }
    __syncthreads();

    #pragma unroll
    for (int rr = 0; rr < 8; ++rr) {
        int row = wv * 8 + rr;
        int qws = row >> 5, ql = row & 31;
        float mg[4], M = -3.0e38f;
        #pragma unroll
        for (int gg = 0; gg < 4; ++gg) {
            mg[gg] = mlp[(gg * 2 + qws) * 64 + ql];
            M = fmaxf(M, mg[gg]);
        }
        float L = 0.0f, f[4];
        #pragma unroll
        for (int gg = 0; gg < 4; ++gg) {
            f[gg] = EXP2(mg[gg] - M);
            L += f[gg] * mlp[(gg * 2 + qws) * 64 + 32 + ql];
        }
        float inv = 1.0f / L;
        f32x2 o = { 0.0f, 0.0f };
        #pragma unroll
        for (int gg = 0; gg < 4; ++gg) {
            f32x2 v = *(const f32x2*)&slab[(size_t)((gg * 2 + qws) * 32 + ql) * SLAB_ST + lane * 2];
            o[0] += f[gg] * v[0];
            o[1] += f[gg] * v[1];
        }
        o[0] *= inv; o[1] *= inv;
        *(f32x2*)&Out[((size_t)b * L_DIM + q0 + row) * D_DIM + lane * 2] = o;
    }
}

extern "C" void kernel_launch(void* const* d_in, const int* in_sizes, int n_in,
                              void* d_out, int out_size, void* d_ws, size_t ws_size,
                              hipStream_t stream) {
    const float* Q = (const float*)d_in[0];
    const float* V = (const float*)d_in[1];
    float* Out     = (float*)d_out;
    f16* ws        = (f16*)d_ws;   // needs 4 MiB
    prep_v<<<dim3(B_DIM * (L_DIM / KVB)), dim3(256), 0, stream>>>(V, ws);
    attn_fwd<<<dim3(B_DIM * (L_DIM / 64)), dim3(512), 0, stream>>>(Q, ws, Out);
}